// Round 16
// baseline (90.065 us; speedup 1.0000x reference)
//
#include <hip/hip_runtime.h>
#include <hip/hip_bf16.h>

#define B_ 4
#define T_ 2048
#define E_ 1024
#define H_ 16
#define D_ 64
#define Mtot 8192
#define N2 2048
#define K_ 1024
#define PS_ (B_ * H_ * T_)   // one psum plane
#define NKT 16               // K / 64
#define LOG2E 1.4426950408889634f

typedef __attribute__((ext_vector_type(8))) short short8;
typedef __attribute__((ext_vector_type(4))) float f32x4;
using bf16 = __hip_bfloat16;

__device__ __forceinline__ void async_copy16(const void* g, void* l) {
  __builtin_amdgcn_global_load_lds(
      (const __attribute__((address_space(1))) unsigned int*)g,
      (__attribute__((address_space(3))) unsigned int*)l, 16, 0, 0);
}

// ---------------- fused cast fp32 -> bf16 (g and Wl in one launch) ----------------
__global__ void cast_both(const float* __restrict__ g, const float* __restrict__ wl,
                          ushort* __restrict__ og, ushort* __restrict__ owl) {
  const int n4g = (Mtot * K_) / 4;
  const int tot = n4g + (N2 * K_) / 4;
  int stride = gridDim.x * blockDim.x;
  for (int i = blockIdx.x * blockDim.x + threadIdx.x; i < tot; i += stride) {
    const float4* src = (i < n4g) ? &reinterpret_cast<const float4*>(g)[i]
                                  : &reinterpret_cast<const float4*>(wl)[i - n4g];
    ushort4* dst = (i < n4g) ? &reinterpret_cast<ushort4*>(og)[i]
                             : &reinterpret_cast<ushort4*>(owl)[i - n4g];
    float4 v = *src;
    bf16 a = __float2bfloat16(v.x), b = __float2bfloat16(v.y);
    bf16 c = __float2bfloat16(v.z), d = __float2bfloat16(v.w);
    *dst = make_ushort4(*(ushort*)&a, *(ushort*)&b, *(ushort*)&c, *(ushort*)&d);
  }
}

// ---------------- lift GEMM: 256x256, 4-phase counted-vmcnt (R8 proven, 39.7us) --
// q outputs (f < E_) pre-scaled by log2(e) so attn can use raw v_exp_f32.
#define MFMA_BF16(a, b, c) __builtin_amdgcn_mfma_f32_16x16x32_bf16(a, b, c, 0, 0, 0)

__launch_bounds__(512, 2)
__global__ void lift_gemm(const bf16* __restrict__ A, const bf16* __restrict__ Bm,
                          bf16* __restrict__ qh, bf16* __restrict__ kh) {
  __shared__ __align__(16) char sL[8][16384];
  const int bid = blockIdx.x;
  const int swz = ((bid & 7) << 5) | (bid >> 3);  // XCD-chunked (256 = 8*32)
  const int m0 = (swz >> 3) * 256;
  const int n0 = (swz & 7) * 256;
  const int tid = threadIdx.x;
  const int lane = tid & 63, w = tid >> 6;
  const int wm = w >> 2, wn = w & 3;
  const int lr = lane & 15, lg = lane >> 4;

  f32x4 acc[8][4];
#pragma unroll
  for (int i = 0; i < 8; ++i)
#pragma unroll
    for (int j = 0; j < 4; ++j) acc[i][j] = (f32x4)(0.0f);

  auto stage_half = [&](int slot, const bf16* gsrc, int Rbase, int kcol) {
#pragma unroll
    for (int it = 0; it < 2; ++it) {
      const int o = ((it * 512 + tid) << 4);
      const int lin = o ^ (((o >> 7) & 7) << 4);
      const int r = lin >> 7, cb = lin & 127;
      async_copy16((const char*)gsrc + ((size_t)(Rbase + r) * K_ + kcol) * 2 + cb,
                   &sL[slot][o]);
    }
  };
  auto rd = [&](int slot, int row, int khalf) -> short8 {
    int off = (row << 7) + (khalf << 6) + (lg << 4);
    off ^= (row & 7) << 4;
    return *(const short8*)&sL[slot][off];
  };

  stage_half(0, A, m0, 0);
  stage_half(1, A, m0 + 128, 0);
  stage_half(2, Bm, n0, 0);
  stage_half(3, Bm, n0 + 128, 0);

  short8 af[4][2], bf0[2][2], bf1[2][2];

  for (int kt = 0; kt < NKT; ++kt) {
    const int cb = (kt & 1) << 2;
    const int nb = cb ^ 4;
    const int kcol = (kt + 1) * 64;
    const int aslot = cb + wm;
    const int bslot = cb + 2 + (wn >> 1);
    const int brow = (wn & 1) * 64;

    if (kt + 1 < NKT) {
      stage_half(nb + 0, A, m0, kcol);
      stage_half(nb + 1, A, m0 + 128, kcol);
      asm volatile("s_waitcnt vmcnt(4)" ::: "memory");
    } else {
      asm volatile("s_waitcnt vmcnt(0)" ::: "memory");
    }
    __builtin_amdgcn_sched_barrier(0);
    __builtin_amdgcn_s_barrier();
#pragma unroll
    for (int i = 0; i < 4; ++i) {
      af[i][0] = rd(aslot, i * 16 + lr, 0);
      af[i][1] = rd(aslot, i * 16 + lr, 1);
    }
#pragma unroll
    for (int j = 0; j < 2; ++j) {
      bf0[j][0] = rd(bslot, brow + j * 16 + lr, 0);
      bf0[j][1] = rd(bslot, brow + j * 16 + lr, 1);
    }
    __builtin_amdgcn_s_setprio(1);
#pragma unroll
    for (int i = 0; i < 4; ++i)
#pragma unroll
      for (int j = 0; j < 2; ++j) {
        acc[i][j] = MFMA_BF16(af[i][0], bf0[j][0], acc[i][j]);
        acc[i][j] = MFMA_BF16(af[i][1], bf0[j][1], acc[i][j]);
      }
    __builtin_amdgcn_s_setprio(0);
    __builtin_amdgcn_sched_barrier(0);
    __builtin_amdgcn_s_barrier();

    if (kt + 1 < NKT) {
      stage_half(nb + 2, Bm, n0, kcol);
      stage_half(nb + 3, Bm, n0 + 128, kcol);
    }
#pragma unroll
    for (int j = 0; j < 2; ++j) {
      bf1[j][0] = rd(bslot, brow + (j + 2) * 16 + lr, 0);
      bf1[j][1] = rd(bslot, brow + (j + 2) * 16 + lr, 1);
    }
    __builtin_amdgcn_sched_barrier(0);
    __builtin_amdgcn_s_barrier();
    __builtin_amdgcn_s_setprio(1);
#pragma unroll
    for (int i = 0; i < 4; ++i)
#pragma unroll
      for (int j = 0; j < 2; ++j) {
        acc[i][j + 2] = MFMA_BF16(af[i][0], bf1[j][0], acc[i][j + 2]);
        acc[i][j + 2] = MFMA_BF16(af[i][1], bf1[j][1], acc[i][j + 2]);
      }
    __builtin_amdgcn_s_setprio(0);
    __builtin_amdgcn_sched_barrier(0);
    __builtin_amdgcn_s_barrier();

#pragma unroll
    for (int i = 0; i < 4; ++i) {
      af[i][0] = rd(aslot, (i + 4) * 16 + lr, 0);
      af[i][1] = rd(aslot, (i + 4) * 16 + lr, 1);
    }
    __builtin_amdgcn_sched_barrier(0);
    __builtin_amdgcn_s_barrier();
    __builtin_amdgcn_s_setprio(1);
#pragma unroll
    for (int i = 0; i < 4; ++i)
#pragma unroll
      for (int j = 0; j < 2; ++j) {
        acc[i + 4][j] = MFMA_BF16(af[i][0], bf0[j][0], acc[i + 4][j]);
        acc[i + 4][j] = MFMA_BF16(af[i][1], bf0[j][1], acc[i + 4][j]);
      }
    __builtin_amdgcn_s_setprio(0);
    __builtin_amdgcn_sched_barrier(0);
    __builtin_amdgcn_s_barrier();

    __builtin_amdgcn_s_setprio(1);
#pragma unroll
    for (int i = 0; i < 4; ++i)
#pragma unroll
      for (int j = 0; j < 2; ++j) {
        acc[i + 4][j + 2] = MFMA_BF16(af[i][0], bf1[j][0], acc[i + 4][j + 2]);
        acc[i + 4][j + 2] = MFMA_BF16(af[i][1], bf1[j][1], acc[i + 4][j + 2]);
      }
    __builtin_amdgcn_s_setprio(0);
    __builtin_amdgcn_sched_barrier(0);
    __builtin_amdgcn_s_barrier();
  }

  const float qscale = (n0 < E_) ? LOG2E : 1.0f;  // block-uniform (256 | E_)
#pragma unroll
  for (int mi = 0; mi < 8; ++mi) {
#pragma unroll
    for (int ni = 0; ni < 4; ++ni) {
#pragma unroll
      for (int r = 0; r < 4; ++r) {
        int m = m0 + wm * 128 + mi * 16 + lg * 4 + r;
        int f = n0 + wn * 64 + ni * 16 + lr;
        bf16 bv = __float2bfloat16(acc[mi][ni][r] * qscale);
        int b = m >> 11, t = m & (T_ - 1);
        int hh = (f & (E_ - 1)) >> 6, d = f & (D_ - 1);
        bf16* dst = (f < E_) ? qh : kh;
        dst[((((size_t)b * H_ + hh) * T_) + t) * D_ + d] = bv;
      }
    }
  }
}

// ---------------- causal LSE: split-4 KV, 64-key tiles, 2-wave blocks ------------
// Grid 8192 = (qt 0..31 desc) x (bh 64) x (s 0..3). Block = 2 waves x 32 q rows.
// Smaller barrier groups (2 waves) -> more independent blocks per CU for latency
// hiding; K-tile shared 2x via LDS (double-buffered, swizzled, counted-vmcnt).
__launch_bounds__(128)
__global__ void attn_lse(const bf16* __restrict__ qh, const bf16* __restrict__ kh,
                         float* __restrict__ psum) {
  __shared__ __align__(16) char sK[2][8192];
  const int bid = blockIdx.x;
  const int qt = 31 - (bid >> 8);        // heavy q-blocks dispatched first
  const int rem = bid & 255;
  const int bh = rem >> 2;
  const int s = rem & 3;
  const int tid = threadIdx.x;
  const int lane = tid & 63, w = tid >> 6;         // w in {0,1}
  const int lr = lane & 15, lg = lane >> 4;
  const int qbase = qt * 64 + w * 32;

  const bf16* qp = qh + ((size_t)bh * T_ + qbase) * D_;
  short8 qf[2][2];
#pragma unroll
  for (int f = 0; f < 2; ++f)
#pragma unroll
    for (int h = 0; h < 2; ++h)
      qf[f][h] = *(const short8*)&qp[(size_t)(f * 16 + lr) * D_ + h * 32 + lg * 8];

  float l[2][4];
#pragma unroll
  for (int f = 0; f < 2; ++f)
#pragma unroll
    for (int r = 0; r < 4; ++r) l[f][r] = 0.0f;

  const char* kbase = (const char*)(kh + (size_t)bh * T_ * D_);
  const int nfullw = qt;                 // both waves' diagonal 64-key tile
  const int nt = (s <= qt) ? ((qt - s) >> 2) + 1 : 0;  // block-uniform

  // stage 64-key tile (8KB) with 128 threads: 4 x 16B per thread
#define STAGE_K(bi, kt_)                                                      \
  do {                                                                        \
    const char* kp_ = kbase + (size_t)(kt_) * (64 * D_ * 2);                  \
    _Pragma("unroll") for (int it = 0; it < 4; ++it) {                        \
      const int o = ((w * 4 + it) << 10) | (lane << 4);                       \
      const int lin = o ^ (((o >> 7) & 7) << 4);                              \
      async_copy16(kp_ + lin, (char*)&sK[bi][0] + o);                         \
    }                                                                         \
  } while (0)

  auto krd = [&](const char* kb, int row, int khalf) -> short8 {
    int off = (row << 7) + (khalf << 6) + (lg << 4);
    off ^= (row & 7) << 4;
    return *(const short8*)(kb + off);
  };

  int cur = 0;
  if (nt > 0) STAGE_K(0, s);
  for (int i = 0; i < nt; ++i) {
    if (i + 1 < nt) {
      STAGE_K(cur ^ 1, s + 4 * (i + 1));               // prefetch next tile
      asm volatile("s_waitcnt vmcnt(4)" ::: "memory"); // tile i landed; next in flight
    } else {
      asm volatile("s_waitcnt vmcnt(0)" ::: "memory");
    }
    __builtin_amdgcn_sched_barrier(0);
    __builtin_amdgcn_s_barrier();                      // both waves' tile-i loads done

    const int kt = s + 4 * i;
    {
      const char* kb = &sK[cur][0];
      short8 kf[4][2];
#pragma unroll
      for (int j = 0; j < 4; ++j) {
        kf[j][0] = krd(kb, j * 16 + lr, 0);
        kf[j][1] = krd(kb, j * 16 + lr, 1);
      }
      f32x4 sc[2][4];
#pragma unroll
      for (int f = 0; f < 2; ++f)
#pragma unroll
        for (int j = 0; j < 4; ++j) sc[f][j] = (f32x4)(0.0f);
#pragma unroll
      for (int j = 0; j < 4; ++j) {
        sc[0][j] = MFMA_BF16(qf[0][0], kf[j][0], sc[0][j]);
        sc[0][j] = MFMA_BF16(qf[0][1], kf[j][1], sc[0][j]);
        sc[1][j] = MFMA_BF16(qf[1][0], kf[j][0], sc[1][j]);
        sc[1][j] = MFMA_BF16(qf[1][1], kf[j][1], sc[1][j]);
      }
      if (kt < nfullw) {
#pragma unroll
        for (int f = 0; f < 2; ++f)
#pragma unroll
          for (int j = 0; j < 4; ++j)
#pragma unroll
            for (int r = 0; r < 4; ++r)
              l[f][r] += __builtin_amdgcn_exp2f(sc[f][j][r]);
      } else {
#pragma unroll
        for (int f = 0; f < 2; ++f)
#pragma unroll
          for (int j = 0; j < 4; ++j)
#pragma unroll
            for (int r = 0; r < 4; ++r) {
              int qrow = qbase + f * 16 + lg * 4 + r;
              int key = kt * 64 + j * 16 + lr;
              float a = (key <= qrow) ? sc[f][j][r] : -INFINITY;
              l[f][r] += __builtin_amdgcn_exp2f(a);  // exp2(-inf) == 0
            }
      }
    }
    __builtin_amdgcn_sched_barrier(0);
    __builtin_amdgcn_s_barrier();                      // reads of sK[cur] done
    cur ^= 1;
  }

  // cross-lane (lr) reduce and store partial sums (always write, even zero)
#pragma unroll
  for (int f = 0; f < 2; ++f)
#pragma unroll
    for (int r = 0; r < 4; ++r) {
      float v = l[f][r];
      v += __shfl_xor(v, 1);
      v += __shfl_xor(v, 2);
      v += __shfl_xor(v, 4);
      v += __shfl_xor(v, 8);
      if (lr == 0)
        psum[(size_t)s * PS_ + (size_t)bh * T_ + qbase + f * 16 + lg * 4 + r] = v;
    }
}

// ---------------- final: out[b,t] = sum_h log(sum_s psum) * cw[h] ----------------
__global__ void proj_out(const float* __restrict__ psum, const float* __restrict__ Wp,
                         float* __restrict__ out) {
  __shared__ float cw[H_];
  int tid = threadIdx.x;
  if (tid < H_) {
    float s = 0.0f;
    for (int g = 0; g < H_; ++g) s += Wp[g * H_ + tid];
    cw[tid] = s;
  }
  __syncthreads();
  int idx = blockIdx.x * blockDim.x + tid;  // b*T + t
  int b = idx >> 11, t = idx & (T_ - 1);
  float acc = 0.0f;
#pragma unroll
  for (int h = 0; h < H_; ++h) {
    size_t base = ((size_t)(b * H_ + h) * T_) + t;
    float v = psum[base] + psum[PS_ + base] + psum[2 * (size_t)PS_ + base] +
              psum[3 * (size_t)PS_ + base];
    acc += __logf(v) * cw[h];
  }
  out[idx] = acc;
}

// ---------------- launch ----------------
extern "C" void kernel_launch(void* const* d_in, const int* in_sizes, int n_in,
                              void* d_out, int out_size, void* d_ws, size_t ws_size,
                              hipStream_t stream) {
  (void)in_sizes; (void)n_in; (void)out_size; (void)ws_size;
  const float* g  = (const float*)d_in[0];   // [B,T,E] fp32
  const float* Wl = (const float*)d_in[1];   // [2E,E] fp32
  const float* Wp = (const float*)d_in[2];   // [H,H] fp32
  float* out = (float*)d_out;                // [B*T] fp32

  char* ws = (char*)d_ws;
  size_t off = 0;
  bf16* g_bf  = (bf16*)(ws + off); off += (size_t)Mtot * K_ * 2;
  bf16* wl_bf = (bf16*)(ws + off); off += (size_t)N2 * K_ * 2;
  bf16* qh    = (bf16*)(ws + off); off += (size_t)B_ * H_ * T_ * D_ * 2;
  bf16* kh    = (bf16*)(ws + off); off += (size_t)B_ * H_ * T_ * D_ * 2;
  float* psum = (float*)(ws + off);          // 4 planes x 512KB = 2MB

  cast_both<<<2560, 256, 0, stream>>>(g, Wl, (ushort*)g_bf, (ushort*)wl_bf);

  lift_gemm<<<256, 512, 0, stream>>>(g_bf, wl_bf, qh, kh);

  attn_lse<<<8192, 128, 0, stream>>>(qh, kh, psum);

  proj_out<<<(B_ * T_) / 256, 256, 0, stream>>>(psum, Wp, out);
}

// Round 17
// 87.531 us; speedup vs baseline: 1.0290x; 1.0290x over previous
//
#include <hip/hip_runtime.h>
#include <hip/hip_bf16.h>

#define B_ 4
#define T_ 2048
#define E_ 1024
#define H_ 16
#define D_ 64
#define Mtot 8192
#define N2 2048
#define K_ 1024
#define PS_ (B_ * H_ * T_)   // one psum plane
#define NKT 16               // K / 64
#define LOG2E 1.4426950408889634f

typedef __attribute__((ext_vector_type(8))) short short8;
typedef __attribute__((ext_vector_type(4))) float f32x4;
using bf16 = __hip_bfloat16;

__device__ __forceinline__ void async_copy16(const void* g, void* l) {
  __builtin_amdgcn_global_load_lds(
      (const __attribute__((address_space(1))) unsigned int*)g,
      (__attribute__((address_space(3))) unsigned int*)l, 16, 0, 0);
}

// ---------------- cast fp32 -> bf16 (vectorized) ----------------
__global__ void cast_f32_to_bf16(const float* __restrict__ in, ushort* __restrict__ out, int n4) {
  int stride = gridDim.x * blockDim.x;
  for (int i = blockIdx.x * blockDim.x + threadIdx.x; i < n4; i += stride) {
    float4 v = reinterpret_cast<const float4*>(in)[i];
    bf16 a = __float2bfloat16(v.x), b = __float2bfloat16(v.y);
    bf16 c = __float2bfloat16(v.z), d = __float2bfloat16(v.w);
    ushort4 o = make_ushort4(*(ushort*)&a, *(ushort*)&b, *(ushort*)&c, *(ushort*)&d);
    reinterpret_cast<ushort4*>(out)[i] = o;
  }
}

// ---------------- lift GEMM: 256x256, 4-phase counted-vmcnt (R8 proven, 39.7us) --
// q outputs (f < E_) pre-scaled by log2(e) so attn can use raw v_exp_f32.
#define MFMA_BF16(a, b, c) __builtin_amdgcn_mfma_f32_16x16x32_bf16(a, b, c, 0, 0, 0)

__launch_bounds__(512, 2)
__global__ void lift_gemm(const bf16* __restrict__ A, const bf16* __restrict__ Bm,
                          bf16* __restrict__ qh, bf16* __restrict__ kh) {
  __shared__ __align__(16) char sL[8][16384];
  const int bid = blockIdx.x;
  const int swz = ((bid & 7) << 5) | (bid >> 3);  // XCD-chunked (256 = 8*32)
  const int m0 = (swz >> 3) * 256;
  const int n0 = (swz & 7) * 256;
  const int tid = threadIdx.x;
  const int lane = tid & 63, w = tid >> 6;
  const int wm = w >> 2, wn = w & 3;
  const int lr = lane & 15, lg = lane >> 4;

  f32x4 acc[8][4];
#pragma unroll
  for (int i = 0; i < 8; ++i)
#pragma unroll
    for (int j = 0; j < 4; ++j) acc[i][j] = (f32x4)(0.0f);

  auto stage_half = [&](int slot, const bf16* gsrc, int Rbase, int kcol) {
#pragma unroll
    for (int it = 0; it < 2; ++it) {
      const int o = ((it * 512 + tid) << 4);
      const int lin = o ^ (((o >> 7) & 7) << 4);
      const int r = lin >> 7, cb = lin & 127;
      async_copy16((const char*)gsrc + ((size_t)(Rbase + r) * K_ + kcol) * 2 + cb,
                   &sL[slot][o]);
    }
  };
  auto rd = [&](int slot, int row, int khalf) -> short8 {
    int off = (row << 7) + (khalf << 6) + (lg << 4);
    off ^= (row & 7) << 4;
    return *(const short8*)&sL[slot][off];
  };

  stage_half(0, A, m0, 0);
  stage_half(1, A, m0 + 128, 0);
  stage_half(2, Bm, n0, 0);
  stage_half(3, Bm, n0 + 128, 0);

  short8 af[4][2], bf0[2][2], bf1[2][2];

  for (int kt = 0; kt < NKT; ++kt) {
    const int cb = (kt & 1) << 2;
    const int nb = cb ^ 4;
    const int kcol = (kt + 1) * 64;
    const int aslot = cb + wm;
    const int bslot = cb + 2 + (wn >> 1);
    const int brow = (wn & 1) * 64;

    if (kt + 1 < NKT) {
      stage_half(nb + 0, A, m0, kcol);
      stage_half(nb + 1, A, m0 + 128, kcol);
      asm volatile("s_waitcnt vmcnt(4)" ::: "memory");
    } else {
      asm volatile("s_waitcnt vmcnt(0)" ::: "memory");
    }
    __builtin_amdgcn_sched_barrier(0);
    __builtin_amdgcn_s_barrier();
#pragma unroll
    for (int i = 0; i < 4; ++i) {
      af[i][0] = rd(aslot, i * 16 + lr, 0);
      af[i][1] = rd(aslot, i * 16 + lr, 1);
    }
#pragma unroll
    for (int j = 0; j < 2; ++j) {
      bf0[j][0] = rd(bslot, brow + j * 16 + lr, 0);
      bf0[j][1] = rd(bslot, brow + j * 16 + lr, 1);
    }
    __builtin_amdgcn_s_setprio(1);
#pragma unroll
    for (int i = 0; i < 4; ++i)
#pragma unroll
      for (int j = 0; j < 2; ++j) {
        acc[i][j] = MFMA_BF16(af[i][0], bf0[j][0], acc[i][j]);
        acc[i][j] = MFMA_BF16(af[i][1], bf0[j][1], acc[i][j]);
      }
    __builtin_amdgcn_s_setprio(0);
    __builtin_amdgcn_sched_barrier(0);
    __builtin_amdgcn_s_barrier();

    if (kt + 1 < NKT) {
      stage_half(nb + 2, Bm, n0, kcol);
      stage_half(nb + 3, Bm, n0 + 128, kcol);
    }
#pragma unroll
    for (int j = 0; j < 2; ++j) {
      bf1[j][0] = rd(bslot, brow + (j + 2) * 16 + lr, 0);
      bf1[j][1] = rd(bslot, brow + (j + 2) * 16 + lr, 1);
    }
    __builtin_amdgcn_sched_barrier(0);
    __builtin_amdgcn_s_barrier();
    __builtin_amdgcn_s_setprio(1);
#pragma unroll
    for (int i = 0; i < 4; ++i)
#pragma unroll
      for (int j = 0; j < 2; ++j) {
        acc[i][j + 2] = MFMA_BF16(af[i][0], bf1[j][0], acc[i][j + 2]);
        acc[i][j + 2] = MFMA_BF16(af[i][1], bf1[j][1], acc[i][j + 2]);
      }
    __builtin_amdgcn_s_setprio(0);
    __builtin_amdgcn_sched_barrier(0);
    __builtin_amdgcn_s_barrier();

#pragma unroll
    for (int i = 0; i < 4; ++i) {
      af[i][0] = rd(aslot, (i + 4) * 16 + lr, 0);
      af[i][1] = rd(aslot, (i + 4) * 16 + lr, 1);
    }
    __builtin_amdgcn_sched_barrier(0);
    __builtin_amdgcn_s_barrier();
    __builtin_amdgcn_s_setprio(1);
#pragma unroll
    for (int i = 0; i < 4; ++i)
#pragma unroll
      for (int j = 0; j < 2; ++j) {
        acc[i + 4][j] = MFMA_BF16(af[i][0], bf0[j][0], acc[i + 4][j]);
        acc[i + 4][j] = MFMA_BF16(af[i][1], bf0[j][1], acc[i + 4][j]);
      }
    __builtin_amdgcn_s_setprio(0);
    __builtin_amdgcn_sched_barrier(0);
    __builtin_amdgcn_s_barrier();

    __builtin_amdgcn_s_setprio(1);
#pragma unroll
    for (int i = 0; i < 4; ++i)
#pragma unroll
      for (int j = 0; j < 2; ++j) {
        acc[i + 4][j + 2] = MFMA_BF16(af[i][0], bf1[j][0], acc[i + 4][j + 2]);
        acc[i + 4][j + 2] = MFMA_BF16(af[i][1], bf1[j][1], acc[i + 4][j + 2]);
      }
    __builtin_amdgcn_s_setprio(0);
    __builtin_amdgcn_sched_barrier(0);
    __builtin_amdgcn_s_barrier();
  }

  const float qscale = (n0 < E_) ? LOG2E : 1.0f;  // block-uniform (256 | E_)
#pragma unroll
  for (int mi = 0; mi < 8; ++mi) {
#pragma unroll
    for (int ni = 0; ni < 4; ++ni) {
#pragma unroll
      for (int r = 0; r < 4; ++r) {
        int m = m0 + wm * 128 + mi * 16 + lg * 4 + r;
        int f = n0 + wn * 64 + ni * 16 + lr;
        bf16 bv = __float2bfloat16(acc[mi][ni][r] * qscale);
        int b = m >> 11, t = m & (T_ - 1);
        int hh = (f & (E_ - 1)) >> 6, d = f & (D_ - 1);
        bf16* dst = (f < E_) ? qh : kh;
        dst[((((size_t)b * H_ + hh) * T_) + t) * D_ + d] = bv;
      }
    }
  }
}

// ---------------- causal LSE: split-4 KV, 64-key tiles, counted-vmcnt + setprio --
#define LSE_QT 128

__launch_bounds__(256)
__global__ void attn_lse(const bf16* __restrict__ qh, const bf16* __restrict__ kh,
                         float* __restrict__ psum) {
  __shared__ __align__(16) char sK[2][8192];
  const int bid = blockIdx.x;
  const int qt = 15 - (bid >> 8);        // heavy q-tiles dispatched first
  const int rem = bid & 255;
  const int bh = rem >> 2;
  const int s = rem & 3;
  const int tid = threadIdx.x;
  const int lane = tid & 63, w = tid >> 6;
  const int lr = lane & 15, lg = lane >> 4;
  const int qbase = qt * LSE_QT + w * 32;

  const bf16* qp = qh + ((size_t)bh * T_ + qbase) * D_;
  short8 qf[2][2];
#pragma unroll
  for (int f = 0; f < 2; ++f)
#pragma unroll
    for (int h = 0; h < 2; ++h)
      qf[f][h] = *(const short8*)&qp[(size_t)(f * 16 + lr) * D_ + h * 32 + lg * 8];

  float l[2][4];
#pragma unroll
  for (int f = 0; f < 2; ++f)
#pragma unroll
    for (int r = 0; r < 4; ++r) l[f][r] = 0.0f;

  const char* kbase = (const char*)(kh + (size_t)bh * T_ * D_);
  const int nfullw = qbase >> 6;         // wave's diagonal 64-key tile
  const int maxk = 2 * qt + 1;           // largest tile any wave in block needs
  const int nt = (s <= maxk) ? ((maxk - s) >> 2) + 1 : 0;  // block-uniform

#define STAGE_K(bi, kt_)                                                      \
  do {                                                                        \
    const char* kp_ = kbase + (size_t)(kt_) * (64 * D_ * 2);                  \
    _Pragma("unroll") for (int it = 0; it < 2; ++it) {                        \
      const int o = ((w * 2 + it) << 10) | (lane << 4);                       \
      const int lin = o ^ (((o >> 7) & 7) << 4);                              \
      async_copy16(kp_ + lin, (char*)&sK[bi][0] + ((w * 2 + it) << 10));      \
    }                                                                         \
  } while (0)

  auto krd = [&](const char* kb, int row, int khalf) -> short8 {
    int off = (row << 7) + (khalf << 6) + (lg << 4);
    off ^= (row & 7) << 4;
    return *(const short8*)(kb + off);
  };

  int cur = 0;
  if (nt > 0) STAGE_K(0, s);
  for (int i = 0; i < nt; ++i) {
    if (i + 1 < nt) {
      STAGE_K(cur ^ 1, s + 4 * (i + 1));               // prefetch next tile
      asm volatile("s_waitcnt vmcnt(2)" ::: "memory"); // tile i landed; next in flight
    } else {
      asm volatile("s_waitcnt vmcnt(0)" ::: "memory");
    }
    __builtin_amdgcn_sched_barrier(0);
    __builtin_amdgcn_s_barrier();                      // all waves' tile-i loads done

    const int kt = s + 4 * i;
    if (kt <= nfullw) {
      const char* kb = &sK[cur][0];
      short8 kf[4][2];
#pragma unroll
      for (int j = 0; j < 4; ++j) {
        kf[j][0] = krd(kb, j * 16 + lr, 0);
        kf[j][1] = krd(kb, j * 16 + lr, 1);
      }
      f32x4 sc[2][4];
#pragma unroll
      for (int f = 0; f < 2; ++f)
#pragma unroll
        for (int j = 0; j < 4; ++j) sc[f][j] = (f32x4)(0.0f);
      __builtin_amdgcn_s_setprio(1);   // T5: prioritize MFMA cluster over
#pragma unroll                          // staging-phase waves of other blocks
      for (int j = 0; j < 4; ++j) {
        sc[0][j] = MFMA_BF16(qf[0][0], kf[j][0], sc[0][j]);
        sc[0][j] = MFMA_BF16(qf[0][1], kf[j][1], sc[0][j]);
        sc[1][j] = MFMA_BF16(qf[1][0], kf[j][0], sc[1][j]);
        sc[1][j] = MFMA_BF16(qf[1][1], kf[j][1], sc[1][j]);
      }
      __builtin_amdgcn_s_setprio(0);
      if (kt < nfullw) {
#pragma unroll
        for (int f = 0; f < 2; ++f)
#pragma unroll
          for (int j = 0; j < 4; ++j)
#pragma unroll
            for (int r = 0; r < 4; ++r)
              l[f][r] += __builtin_amdgcn_exp2f(sc[f][j][r]);
      } else {
#pragma unroll
        for (int f = 0; f < 2; ++f)
#pragma unroll
          for (int j = 0; j < 4; ++j)
#pragma unroll
            for (int r = 0; r < 4; ++r) {
              int qrow = qbase + f * 16 + lg * 4 + r;
              int key = kt * 64 + j * 16 + lr;
              float a = (key <= qrow) ? sc[f][j][r] : -INFINITY;
              l[f][r] += __builtin_amdgcn_exp2f(a);  // exp2(-inf) == 0
            }
      }
    }
    __builtin_amdgcn_sched_barrier(0);
    __builtin_amdgcn_s_barrier();                      // reads of sK[cur] done
    cur ^= 1;
  }

  // cross-lane (lr) reduce and store partial sums (always write, even zero)
#pragma unroll
  for (int f = 0; f < 2; ++f)
#pragma unroll
    for (int r = 0; r < 4; ++r) {
      float v = l[f][r];
      v += __shfl_xor(v, 1);
      v += __shfl_xor(v, 2);
      v += __shfl_xor(v, 4);
      v += __shfl_xor(v, 8);
      if (lr == 0)
        psum[(size_t)s * PS_ + (size_t)bh * T_ + qbase + f * 16 + lg * 4 + r] = v;
    }
}

// ---------------- final: out[b,t] = sum_h log(sum_s psum) * cw[h] ----------------
__global__ void proj_out(const float* __restrict__ psum, const float* __restrict__ Wp,
                         float* __restrict__ out) {
  __shared__ float cw[H_];
  int tid = threadIdx.x;
  if (tid < H_) {
    float s = 0.0f;
    for (int g = 0; g < H_; ++g) s += Wp[g * H_ + tid];
    cw[tid] = s;
  }
  __syncthreads();
  int idx = blockIdx.x * blockDim.x + tid;  // b*T + t
  int b = idx >> 11, t = idx & (T_ - 1);
  float acc = 0.0f;
#pragma unroll
  for (int h = 0; h < H_; ++h) {
    size_t base = ((size_t)(b * H_ + h) * T_) + t;
    float v = psum[base] + psum[PS_ + base] + psum[2 * (size_t)PS_ + base] +
              psum[3 * (size_t)PS_ + base];
    acc += __logf(v) * cw[h];
  }
  out[idx] = acc;
}

// ---------------- launch ----------------
extern "C" void kernel_launch(void* const* d_in, const int* in_sizes, int n_in,
                              void* d_out, int out_size, void* d_ws, size_t ws_size,
                              hipStream_t stream) {
  (void)in_sizes; (void)n_in; (void)out_size; (void)ws_size;
  const float* g  = (const float*)d_in[0];   // [B,T,E] fp32
  const float* Wl = (const float*)d_in[1];   // [2E,E] fp32
  const float* Wp = (const float*)d_in[2];   // [H,H] fp32
  float* out = (float*)d_out;                // [B*T] fp32

  char* ws = (char*)d_ws;
  size_t off = 0;
  bf16* g_bf  = (bf16*)(ws + off); off += (size_t)Mtot * K_ * 2;
  bf16* wl_bf = (bf16*)(ws + off); off += (size_t)N2 * K_ * 2;
  bf16* qh    = (bf16*)(ws + off); off += (size_t)B_ * H_ * T_ * D_ * 2;
  bf16* kh    = (bf16*)(ws + off); off += (size_t)B_ * H_ * T_ * D_ * 2;
  float* psum = (float*)(ws + off);          // 4 planes x 512KB = 2MB

  cast_f32_to_bf16<<<2048, 256, 0, stream>>>(g,  (ushort*)g_bf,  (Mtot * K_) / 4);
  cast_f32_to_bf16<<<512,  256, 0, stream>>>(Wl, (ushort*)wl_bf, (N2 * K_) / 4);

  lift_gemm<<<256, 512, 0, stream>>>(g_bf, wl_bf, qh, kh);

  attn_lse<<<4096, 256, 0, stream>>>(qh, kh, psum);

  proj_out<<<(B_ * T_) / 256, 256, 0, stream>>>(psum, Wp, out);
}